// Round 4
// baseline (2329.786 us; speedup 1.0000x reference)
//
#include <hip/hip_runtime.h>
#include <cmath>

// PropConv: K=10 hop gated propagation on a fixed graph + output MLP.
// R4: column-panel hops. h stored panel-major [P=8][N][16] so each panel
// (3.2 MB) fits a per-XCD L2 (4 MiB); grid=(nodes/32, panel) dispatches
// panel-phase-major -> gathers served by L2 (34.5 TB/s) instead of the
// L3 ceiling (~7 TB/s) that bounded R3. One edge gather = one 64B line
// (4-lane segment x float4). Wave = 8 nodes, 16 edges in parallel.

#define NNODES 50000
#define NEDGES 1600000
#define DD 128
#define KHOPS 10
#define NPAN 8
#define PANW 16      // cols per panel
#define ALPHA 0.1f

// 8-entry gate table: gate MLP has only 8 distinct inputs (etypes).
__global__ void gate_kernel(const float* __restrict__ emb, const float* __restrict__ We1,
                            const float* __restrict__ be1, const float* __restrict__ We2,
                            const float* __restrict__ be2, float* __restrict__ gate) {
    int t = threadIdx.x;
    if (t >= 8) return;
    float acc2 = 0.0f;
    for (int j = 0; j < 32; j++) {
        float a = be1[j];
        for (int k = 0; k < DD; k++) a += emb[t * DD + k] * We1[k * 32 + j];
        float g = 0.5f * a * (1.0f + erff(a * 0.70710678118654752f));  // exact GELU
        acc2 += g * We2[j];
    }
    acc2 += be2[0];
    gate[t] = 1.0f + 1.0f / (1.0f + expf(-acc2));   // 1 + sigmoid
}

__global__ void deg_in_kernel(const int* __restrict__ dst, int* __restrict__ incnt, int E) {
    int e = blockIdx.x * blockDim.x + threadIdx.x;
    if (e < E) atomicAdd(&incnt[dst[e]], 1);
}

// Single-block exclusive scan of in-degree counts -> row_ptr.
__global__ __launch_bounds__(1024) void scan_kernel(const int* __restrict__ cnt,
                                                    int* __restrict__ row_ptr, int N, int E) {
    __shared__ int part[1024];
    int t = threadIdx.x;
    int chunk = (N + 1023) / 1024;
    int beg = t * chunk; if (beg > N) beg = N;
    int end = beg + chunk; if (end > N) end = N;
    int s = 0;
    for (int i = beg; i < end; i++) s += cnt[i];
    part[t] = s;
    __syncthreads();
    for (int off = 1; off < 1024; off <<= 1) {
        int v = 0;
        if (t >= off) v = part[t - off];
        __syncthreads();
        if (t >= off) part[t] += v;
        __syncthreads();
    }
    int excl = (t == 0) ? 0 : part[t - 1];
    for (int i = beg; i < end; i++) { row_ptr[i] = excl; excl += cnt[i]; }
    if (t == 0) row_ptr[N] = E;
}

// Bucket edges by dst. 4B payload: src (16b) | etype (<<16). Also builds outcnt.
__global__ void scatter_kernel(const int* __restrict__ src, const int* __restrict__ dst,
                               const int* __restrict__ ef, const int* __restrict__ row_ptr,
                               int* __restrict__ cursor, int* __restrict__ outcnt,
                               int* __restrict__ epay, int E) {
    int e = blockIdx.x * blockDim.x + threadIdx.x;
    if (e >= E) return;
    int d = dst[e];
    int s = src[e];
    int pos = row_ptr[d] + atomicAdd(&cursor[d], 1);
    epay[pos] = s | (ef[e] << 16);
    atomicAdd(&outcnt[s], 1);
}

// g0[p][n][0:16] = feat[n][p*16:+16] * src_norm[n]  (panel-major, pre-scaled).
__global__ void scale_kernel(const float* __restrict__ feat, const int* __restrict__ outcnt,
                             float* __restrict__ g0, int N) {
    int o = blockIdx.x * blockDim.x + threadIdx.x;   // float4 units, panel-major flat
    if (o >= N * 32) return;
    int panel = o / (N * 4);
    int rem = o - panel * (N * 4);
    int node = rem >> 2;
    int q = rem & 3;
    int oc = outcnt[node]; if (oc < 1) oc = 1;
    float sn = rsqrtf((float)oc);
    float4 v = ((const float4*)feat)[node * 32 + panel * 4 + q];
    v.x *= sn; v.y *= sn; v.z *= sn; v.w *= sn;
    ((float4*)g0)[o] = v;
}

// Wave = 8 nodes x 1 panel. 16 four-lane segments process 16 edges in
// parallel; each edge gather is one 64B line from the L2-resident panel.
// Payload chunks (<=64 edges/node) preloaded into regs up-front so all
// gathers are independent. Epilogue vectorized on lanes 0-31 (8 nodes x 16B).
__global__ __launch_bounds__(256) void hop_kernel(const float* __restrict__ g_in,
                                                  const float* __restrict__ feat0,
                                                  const int* __restrict__ incnt,
                                                  const int* __restrict__ outcnt,
                                                  const float* __restrict__ gate_g,
                                                  const int* __restrict__ row_ptr,
                                                  const int* __restrict__ epay,
                                                  float* __restrict__ g_out, int N, int last) {
    __shared__ float gateL[8];
    if (threadIdx.x < 8) gateL[threadIdx.x] = gate_g[threadIdx.x];
    __syncthreads();
    int wv = threadIdx.x >> 6;
    int lane = threadIdx.x & 63;
    int pan = blockIdx.y;
    int ng = (blockIdx.x * 4 + wv) * 8;
    if (ng >= N) return;
    int seg = lane >> 2;
    int q = lane & 3;
    const float* gp = g_in + (size_t)pan * N * PANW;

    int idx = ng + (lane < 9 ? lane : 8);
    if (idx > N) idx = N;
    int rp = row_ptr[idx];

    int beg[8], cnt[8], pay[8];
#pragma unroll
    for (int i = 0; i < 8; i++) {
        beg[i] = __shfl(rp, i, 64);
        cnt[i] = __shfl(rp, i + 1, 64) - beg[i];
    }
#pragma unroll
    for (int i = 0; i < 8; i++) {
        pay[i] = 0;
        if (lane < cnt[i]) pay[i] = epay[beg[i] + lane];
    }

    float4 res = {0.f, 0.f, 0.f, 0.f};
#pragma unroll
    for (int i = 0; i < 8; i++) {
        float4 part = {0.f, 0.f, 0.f, 0.f};
        int n0 = cnt[i] < 64 ? cnt[i] : 64;
        int iters = (n0 + 15) >> 4;               // wave-uniform
        for (int it = 0; it < iters; it++) {
            int j = it * 16 + seg;
            bool valid = j < n0;
            int je = valid ? j : 0;
            int pe = __shfl(pay[i], je, 64);      // all lanes participate
            if (valid) {
                float c = gateL[(unsigned)pe >> 16];
                const float4 v = *(const float4*)(gp + (size_t)(pe & 0xFFFF) * PANW + q * 4);
                part.x += c * v.x; part.y += c * v.y;
                part.z += c * v.z; part.w += c * v.w;
            }
        }
        // rare tail: degree > 64
        for (int base = 64; base < cnt[i]; base += 64) {
            int m = cnt[i] - base; if (m > 64) m = 64;
            int pch = 0;
            if (lane < m) pch = epay[beg[i] + base + lane];
            int it2 = (m + 15) >> 4;
            for (int it = 0; it < it2; it++) {
                int j = it * 16 + seg;
                bool valid = j < m;
                int je = valid ? j : 0;
                int pe = __shfl(pch, je, 64);
                if (valid) {
                    float c = gateL[(unsigned)pe >> 16];
                    const float4 v = *(const float4*)(gp + (size_t)(pe & 0xFFFF) * PANW + q * 4);
                    part.x += c * v.x; part.y += c * v.y;
                    part.z += c * v.z; part.w += c * v.w;
                }
            }
        }
        // reduce across the 16 segments (steps 4,8,16,32)
#pragma unroll
        for (int d = 4; d < 64; d <<= 1) {
            part.x += __shfl_xor(part.x, d, 64);
            part.y += __shfl_xor(part.y, d, 64);
            part.z += __shfl_xor(part.z, d, 64);
            part.w += __shfl_xor(part.w, d, 64);
        }
        if ((lane >> 2) == i) res = part;
    }

    // epilogue: lanes 0-31 hold 8 nodes x 4 float4s
    int node = ng + (lane >> 2);
    if (lane < 32 && node < N) {
        int ic = incnt[node]; if (ic < 1) ic = 1;
        float dn = rsqrtf((float)ic) * (1.0f - ALPHA);
        float4 fv = *(const float4*)(feat0 + (size_t)node * DD + pan * PANW + q * 4);
        float4 h;
        h.x = dn * res.x + ALPHA * fv.x;
        h.y = dn * res.y + ALPHA * fv.y;
        h.z = dn * res.z + ALPHA * fv.z;
        h.w = dn * res.w + ALPHA * fv.w;
        float sc = 1.0f;
        if (!last) { int oc = outcnt[node]; if (oc < 1) oc = 1; sc = rsqrtf((float)oc); }
        h.x *= sc; h.y *= sc; h.z *= sc; h.w *= sc;
        size_t oaddr = last ? ((size_t)node * DD + pan * PANW + q * 4)
                            : ((size_t)pan * N * PANW + (size_t)node * PANW + q * 4);
        *(float4*)(g_out + oaddr) = h;
    }
}

// [N,128]@[128,128] GEMM, f32 vector ALU (no f32 MFMA on CDNA4).
__global__ __launch_bounds__(256) void mlp_kernel(const float* __restrict__ in,
                                                  const float* __restrict__ W,
                                                  const float* __restrict__ bias,
                                                  float* __restrict__ out, int N, int do_gelu) {
    __shared__ float ins[64 * DD];   // 32 KB
    __shared__ float Wt[64 * DD];    // 32 KB
    int tid = threadIdx.x;
    int row0 = blockIdx.x * 64;
    int nrows = N - row0; if (nrows > 64) nrows = 64;
    for (int i = tid; i < nrows * 32; i += 256)
        ((float4*)ins)[i] = ((const float4*)(in + (size_t)row0 * DD))[i];

    int jc = (tid & 31) * 4;
    int rg = (tid >> 5) * 8;
    float acc[8][4];
#pragma unroll
    for (int r = 0; r < 8; r++)
#pragma unroll
        for (int c = 0; c < 4; c++) acc[r][c] = 0.0f;

    for (int k0 = 0; k0 < DD; k0 += 64) {
        __syncthreads();
        for (int i = tid; i < 64 * 32; i += 256)
            ((float4*)Wt)[i] = ((const float4*)(W + (size_t)k0 * DD))[i];
        __syncthreads();
#pragma unroll 2
        for (int k = 0; k < 64; k += 4) {
            float4 wv[4];
#pragma unroll
            for (int i = 0; i < 4; i++) wv[i] = *(const float4*)&Wt[(k + i) * DD + jc];
#pragma unroll
            for (int r = 0; r < 8; r++) {
                float4 a = *(const float4*)&ins[(rg + r) * DD + k0 + k];
                acc[r][0] += a.x * wv[0].x + a.y * wv[1].x + a.z * wv[2].x + a.w * wv[3].x;
                acc[r][1] += a.x * wv[0].y + a.y * wv[1].y + a.z * wv[2].y + a.w * wv[3].y;
                acc[r][2] += a.x * wv[0].z + a.y * wv[1].z + a.z * wv[2].z + a.w * wv[3].z;
                acc[r][3] += a.x * wv[0].w + a.y * wv[1].w + a.z * wv[2].w + a.w * wv[3].w;
            }
        }
    }
    float4 bv = *(const float4*)&bias[jc];
#pragma unroll
    for (int r = 0; r < 8; r++) {
        int row = row0 + rg + r;
        if (row >= N) continue;
        float4 v;
        v.x = acc[r][0] + bv.x; v.y = acc[r][1] + bv.y;
        v.z = acc[r][2] + bv.z; v.w = acc[r][3] + bv.w;
        if (do_gelu) {
            v.x = 0.5f * v.x * (1.0f + erff(v.x * 0.70710678118654752f));
            v.y = 0.5f * v.y * (1.0f + erff(v.y * 0.70710678118654752f));
            v.z = 0.5f * v.z * (1.0f + erff(v.z * 0.70710678118654752f));
            v.w = 0.5f * v.w * (1.0f + erff(v.w * 0.70710678118654752f));
        }
        *(float4*)(out + (size_t)row * DD + jc) = v;
    }
}

extern "C" void kernel_launch(void* const* d_in, const int* in_sizes, int n_in,
                              void* d_out, int out_size, void* d_ws, size_t ws_size,
                              hipStream_t stream) {
    const float* feat = (const float*)d_in[0];
    const int*   e_feat = (const int*)d_in[1];
    const int*   src = (const int*)d_in[2];
    const int*   dst = (const int*)d_in[3];
    const float* emb = (const float*)d_in[4];
    const float* We1 = (const float*)d_in[5];
    const float* be1 = (const float*)d_in[6];
    const float* We2 = (const float*)d_in[7];
    const float* be2 = (const float*)d_in[8];
    const float* W1  = (const float*)d_in[9];
    const float* b1  = (const float*)d_in[10];
    const float* W2  = (const float*)d_in[11];
    const float* b2  = (const float*)d_in[12];
    float* out = (float*)d_out;

    const int N = NNODES, E = NEDGES;
    char* ws = (char*)d_ws;
    size_t off = 0;
    float* ga = (float*)(ws + off);      off += (size_t)N * DD * 4;   // 25.6 MB
    float* gb = (float*)(ws + off);      off += (size_t)N * DD * 4;   // 25.6 MB
    int*   epay = (int*)(ws + off);      off += (size_t)E * 4;        // 6.4 MB
    int*   row_ptr = (int*)(ws + off);   off += (size_t)(N + 1) * 4;
    int*   cnts = (int*)(ws + off);      off += (size_t)3 * N * 4;    // incnt|outcnt|cursor
    float* gate = (float*)(ws + off);    off += 64;
    int* incnt  = cnts;
    int* outcnt = cnts + N;
    int* cursor = cnts + 2 * N;

    hipMemsetAsync(cnts, 0, (size_t)3 * N * 4, stream);
    gate_kernel<<<1, 64, 0, stream>>>(emb, We1, be1, We2, be2, gate);
    deg_in_kernel<<<E / 256, 256, 0, stream>>>(dst, incnt, E);
    scan_kernel<<<1, 1024, 0, stream>>>(incnt, row_ptr, N, E);
    scatter_kernel<<<E / 256, 256, 0, stream>>>(src, dst, e_feat, row_ptr,
                                                cursor, outcnt, epay, E);
    scale_kernel<<<(N * 32 + 255) / 256, 256, 0, stream>>>(feat, outcnt, ga, N);

    dim3 hgrid((N + 31) / 32, NPAN);
    const float* gin = ga;
    float* gout = gb;
    for (int k = 0; k < KHOPS; k++) {
        hop_kernel<<<hgrid, 256, 0, stream>>>(gin, feat, incnt, outcnt, gate,
                                              row_ptr, epay, gout, N, k == KHOPS - 1);
        gin = gout;
        gout = (gout == ga) ? gb : ga;
    }
    // gin = final h (row-major after last hop); gout = free buffer -> hidden.
    float* hidden = gout;
    mlp_kernel<<<(N + 63) / 64, 256, 0, stream>>>(gin, W1, b1, hidden, N, 1);
    mlp_kernel<<<(N + 63) / 64, 256, 0, stream>>>(hidden, W2, b2, out, N, 0);
}

// Round 5
// 1062.416 us; speedup vs baseline: 2.1929x; 2.1929x over previous
//
#include <hip/hip_runtime.h>
#include <cmath>

// PropConv: K=10 hop gated propagation on a fixed graph + output MLP.
// R5: revert R4 panels (refetch+VALU regression). R3 hop structure, but the
// propagated state g is stored as bf16 (row = 256B): halves the ~820MB/hop
// gather traffic that sits on the ~7TB/s L3 service ceiling. All arithmetic,
// residual (feat0), norms, final-hop output and MLP remain f32; only the
// inter-hop state is RNE-rounded to bf16.

#define NNODES 50000
#define NEDGES 1600000
#define DD 128
#define KHOPS 10
#define ALPHA 0.1f

static __device__ __forceinline__ unsigned bf16rne(float x) {
    unsigned u = __float_as_uint(x);
    return (u + 0x7FFFu + ((u >> 16) & 1u)) >> 16;
}
static __device__ __forceinline__ float bf_lo(unsigned w) { return __uint_as_float(w << 16); }
static __device__ __forceinline__ float bf_hi(unsigned w) { return __uint_as_float(w & 0xFFFF0000u); }

// 8-entry gate table: gate MLP has only 8 distinct inputs (etypes).
__global__ void gate_kernel(const float* __restrict__ emb, const float* __restrict__ We1,
                            const float* __restrict__ be1, const float* __restrict__ We2,
                            const float* __restrict__ be2, float* __restrict__ gate) {
    int t = threadIdx.x;
    if (t >= 8) return;
    float acc2 = 0.0f;
    for (int j = 0; j < 32; j++) {
        float a = be1[j];
        for (int k = 0; k < DD; k++) a += emb[t * DD + k] * We1[k * 32 + j];
        float g = 0.5f * a * (1.0f + erff(a * 0.70710678118654752f));  // exact GELU
        acc2 += g * We2[j];
    }
    acc2 += be2[0];
    gate[t] = 1.0f + 1.0f / (1.0f + expf(-acc2));   // 1 + sigmoid
}

__global__ void deg_in_kernel(const int* __restrict__ dst, int* __restrict__ incnt, int E) {
    int e = blockIdx.x * blockDim.x + threadIdx.x;
    if (e < E) atomicAdd(&incnt[dst[e]], 1);
}

// Single-block exclusive scan of in-degree counts -> row_ptr.
__global__ __launch_bounds__(1024) void scan_kernel(const int* __restrict__ cnt,
                                                    int* __restrict__ row_ptr, int N, int E) {
    __shared__ int part[1024];
    int t = threadIdx.x;
    int chunk = (N + 1023) / 1024;
    int beg = t * chunk; if (beg > N) beg = N;
    int end = beg + chunk; if (end > N) end = N;
    int s = 0;
    for (int i = beg; i < end; i++) s += cnt[i];
    part[t] = s;
    __syncthreads();
    for (int off = 1; off < 1024; off <<= 1) {
        int v = 0;
        if (t >= off) v = part[t - off];
        __syncthreads();
        if (t >= off) part[t] += v;
        __syncthreads();
    }
    int excl = (t == 0) ? 0 : part[t - 1];
    for (int i = beg; i < end; i++) { row_ptr[i] = excl; excl += cnt[i]; }
    if (t == 0) row_ptr[N] = E;
}

// Bucket edges by dst. 4B payload: src (16b) | etype (<<16). Also builds outcnt.
__global__ void scatter_kernel(const int* __restrict__ src, const int* __restrict__ dst,
                               const int* __restrict__ ef, const int* __restrict__ row_ptr,
                               int* __restrict__ cursor, int* __restrict__ outcnt,
                               int* __restrict__ epay, int E) {
    int e = blockIdx.x * blockDim.x + threadIdx.x;
    if (e >= E) return;
    int d = dst[e];
    int s = src[e];
    int pos = row_ptr[d] + atomicAdd(&cursor[d], 1);
    epay[pos] = s | (ef[e] << 16);
    atomicAdd(&outcnt[s], 1);
}

// g0 = bf16(feat * src_norm), row-major [N][128] bf16 (256B rows).
__global__ void scale_kernel(const float* __restrict__ feat, const int* __restrict__ outcnt,
                             unsigned* __restrict__ g0, int N) {
    int i = blockIdx.x * blockDim.x + threadIdx.x;   // one float4-group (4 cols)
    if (i >= N * 32) return;
    int row = i >> 5;
    int oc = outcnt[row]; if (oc < 1) oc = 1;
    float sn = rsqrtf((float)oc);
    float4 v = ((const float4*)feat)[i];
    uint2 o;
    o.x = bf16rne(v.x * sn) | (bf16rne(v.y * sn) << 16);
    o.y = bf16rne(v.z * sn) | (bf16rne(v.w * sn) << 16);
    ((uint2*)g0)[i] = o;
}

// Half-wave (32 lanes) per dst node; lane holds uint2 = 4 bf16 cols of the
// 256B row. Payloads loaded coalesced in chunks of 32, broadcast via __shfl;
// x8 unroll -> 8 independent 8B gathers in flight per lane. Epilogue in f32:
// h = .9*dstn*agg + .1*feat0; stores bf16(h*srcn) except last hop -> f32 row.
__global__ __launch_bounds__(256) void hop_kernel(const unsigned* __restrict__ g_in,
                                                  const float* __restrict__ feat0,
                                                  const int* __restrict__ incnt,
                                                  const int* __restrict__ outcnt,
                                                  const float* __restrict__ gate_g,
                                                  const int* __restrict__ row_ptr,
                                                  const int* __restrict__ epay,
                                                  unsigned* __restrict__ g_out_bf,
                                                  float* __restrict__ g_out_f32,
                                                  int N, int last) {
    __shared__ float gateL[8];
    if (threadIdx.x < 8) gateL[threadIdx.x] = gate_g[threadIdx.x];
    __syncthreads();
    int half = threadIdx.x >> 5;     // 0..7
    int lane = threadIdx.x & 31;
    int node = blockIdx.x * 8 + half;
    if (node >= N) return;
    int beg = row_ptr[node], end = row_ptr[node + 1];
    const uint2* gp = (const uint2*)g_in;            // row = 32 uint2
    float a0 = 0.f, a1 = 0.f, a2 = 0.f, a3 = 0.f;
    for (int base = beg; base < end; base += 32) {
        int n = end - base; if (n > 32) n = 32;
        int p = 0;
        if (lane < n) p = epay[base + lane];
        int j = 0;
        for (; j + 8 <= n; j += 8) {
            int pj[8];
#pragma unroll
            for (int u = 0; u < 8; u++) pj[u] = __shfl(p, j + u, 32);
            uint2 v[8];
#pragma unroll
            for (int u = 0; u < 8; u++)
                v[u] = gp[(size_t)(pj[u] & 0xFFFF) * 32 + lane];
#pragma unroll
            for (int u = 0; u < 8; u++) {
                float c = gateL[(unsigned)pj[u] >> 16];
                a0 += c * bf_lo(v[u].x); a1 += c * bf_hi(v[u].x);
                a2 += c * bf_lo(v[u].y); a3 += c * bf_hi(v[u].y);
            }
        }
        for (; j < n; j++) {
            int pj = __shfl(p, j, 32);
            float c = gateL[(unsigned)pj >> 16];
            uint2 v = gp[(size_t)(pj & 0xFFFF) * 32 + lane];
            a0 += c * bf_lo(v.x); a1 += c * bf_hi(v.x);
            a2 += c * bf_lo(v.y); a3 += c * bf_hi(v.y);
        }
    }
    int ic = incnt[node]; if (ic < 1) ic = 1;
    float dn = rsqrtf((float)ic) * (1.0f - ALPHA);
    float4 fv = *(const float4*)(feat0 + (size_t)node * DD + lane * 4);
    float h0 = dn * a0 + ALPHA * fv.x;
    float h1 = dn * a1 + ALPHA * fv.y;
    float h2 = dn * a2 + ALPHA * fv.z;
    float h3 = dn * a3 + ALPHA * fv.w;
    if (last) {
        float4 o = {h0, h1, h2, h3};
        *(float4*)(g_out_f32 + (size_t)node * DD + lane * 4) = o;
    } else {
        int oc = outcnt[node]; if (oc < 1) oc = 1;
        float sc = rsqrtf((float)oc);
        uint2 o;
        o.x = bf16rne(h0 * sc) | (bf16rne(h1 * sc) << 16);
        o.y = bf16rne(h2 * sc) | (bf16rne(h3 * sc) << 16);
        ((uint2*)g_out_bf)[(size_t)node * 32 + lane] = o;
    }
}

// [N,128]@[128,128] GEMM, f32 vector ALU (no f32 MFMA on CDNA4).
__global__ __launch_bounds__(256) void mlp_kernel(const float* __restrict__ in,
                                                  const float* __restrict__ W,
                                                  const float* __restrict__ bias,
                                                  float* __restrict__ out, int N, int do_gelu) {
    __shared__ float ins[64 * DD];   // 32 KB
    __shared__ float Wt[64 * DD];    // 32 KB
    int tid = threadIdx.x;
    int row0 = blockIdx.x * 64;
    int nrows = N - row0; if (nrows > 64) nrows = 64;
    for (int i = tid; i < nrows * 32; i += 256)
        ((float4*)ins)[i] = ((const float4*)(in + (size_t)row0 * DD))[i];

    int jc = (tid & 31) * 4;
    int rg = (tid >> 5) * 8;
    float acc[8][4];
#pragma unroll
    for (int r = 0; r < 8; r++)
#pragma unroll
        for (int c = 0; c < 4; c++) acc[r][c] = 0.0f;

    for (int k0 = 0; k0 < DD; k0 += 64) {
        __syncthreads();
        for (int i = tid; i < 64 * 32; i += 256)
            ((float4*)Wt)[i] = ((const float4*)(W + (size_t)k0 * DD))[i];
        __syncthreads();
#pragma unroll 2
        for (int k = 0; k < 64; k += 4) {
            float4 wv[4];
#pragma unroll
            for (int i = 0; i < 4; i++) wv[i] = *(const float4*)&Wt[(k + i) * DD + jc];
#pragma unroll
            for (int r = 0; r < 8; r++) {
                float4 a = *(const float4*)&ins[(rg + r) * DD + k0 + k];
                acc[r][0] += a.x * wv[0].x + a.y * wv[1].x + a.z * wv[2].x + a.w * wv[3].x;
                acc[r][1] += a.x * wv[0].y + a.y * wv[1].y + a.z * wv[2].y + a.w * wv[3].y;
                acc[r][2] += a.x * wv[0].z + a.y * wv[1].z + a.z * wv[2].z + a.w * wv[3].z;
                acc[r][3] += a.x * wv[0].w + a.y * wv[1].w + a.z * wv[2].w + a.w * wv[3].w;
            }
        }
    }
    float4 bv = *(const float4*)&bias[jc];
#pragma unroll
    for (int r = 0; r < 8; r++) {
        int row = row0 + rg + r;
        if (row >= N) continue;
        float4 v;
        v.x = acc[r][0] + bv.x; v.y = acc[r][1] + bv.y;
        v.z = acc[r][2] + bv.z; v.w = acc[r][3] + bv.w;
        if (do_gelu) {
            v.x = 0.5f * v.x * (1.0f + erff(v.x * 0.70710678118654752f));
            v.y = 0.5f * v.y * (1.0f + erff(v.y * 0.70710678118654752f));
            v.z = 0.5f * v.z * (1.0f + erff(v.z * 0.70710678118654752f));
            v.w = 0.5f * v.w * (1.0f + erff(v.w * 0.70710678118654752f));
        }
        *(float4*)(out + (size_t)row * DD + jc) = v;
    }
}

extern "C" void kernel_launch(void* const* d_in, const int* in_sizes, int n_in,
                              void* d_out, int out_size, void* d_ws, size_t ws_size,
                              hipStream_t stream) {
    const float* feat = (const float*)d_in[0];
    const int*   e_feat = (const int*)d_in[1];
    const int*   src = (const int*)d_in[2];
    const int*   dst = (const int*)d_in[3];
    const float* emb = (const float*)d_in[4];
    const float* We1 = (const float*)d_in[5];
    const float* be1 = (const float*)d_in[6];
    const float* We2 = (const float*)d_in[7];
    const float* be2 = (const float*)d_in[8];
    const float* W1  = (const float*)d_in[9];
    const float* b1  = (const float*)d_in[10];
    const float* W2  = (const float*)d_in[11];
    const float* b2  = (const float*)d_in[12];
    float* out = (float*)d_out;

    const int N = NNODES, E = NEDGES;
    char* ws = (char*)d_ws;
    size_t off = 0;
    unsigned* ga = (unsigned*)(ws + off);  off += (size_t)N * 256;    // 12.8 MB bf16 state
    unsigned* gb = (unsigned*)(ws + off);  off += (size_t)N * 256;    // 12.8 MB bf16 state
    float* hfin = (float*)(ws + off);      off += (size_t)N * DD * 4; // 25.6 MB f32 final h
    int*   epay = (int*)(ws + off);        off += (size_t)E * 4;      // 6.4 MB
    int*   row_ptr = (int*)(ws + off);     off += (size_t)(N + 1) * 4;
    int*   cnts = (int*)(ws + off);        off += (size_t)3 * N * 4;  // incnt|outcnt|cursor
    float* gate = (float*)(ws + off);      off += 64;
    int* incnt  = cnts;
    int* outcnt = cnts + N;
    int* cursor = cnts + 2 * N;
    float* hidden = (float*)ws;   // aliases ga+gb (25.6 MB), free after hops

    hipMemsetAsync(cnts, 0, (size_t)3 * N * 4, stream);
    gate_kernel<<<1, 64, 0, stream>>>(emb, We1, be1, We2, be2, gate);
    deg_in_kernel<<<E / 256, 256, 0, stream>>>(dst, incnt, E);
    scan_kernel<<<1, 1024, 0, stream>>>(incnt, row_ptr, N, E);
    scatter_kernel<<<E / 256, 256, 0, stream>>>(src, dst, e_feat, row_ptr,
                                                cursor, outcnt, epay, E);
    scale_kernel<<<(N * 32 + 255) / 256, 256, 0, stream>>>(feat, outcnt, ga, N);

    const unsigned* gin = ga;
    unsigned* gout = gb;
    for (int k = 0; k < KHOPS; k++) {
        int last = (k == KHOPS - 1);
        hop_kernel<<<(N + 7) / 8, 256, 0, stream>>>(gin, feat, incnt, outcnt, gate,
                                                    row_ptr, epay, gout, hfin, N, last);
        gin = gout;
        gout = (gout == ga) ? gb : ga;
    }
    // hfin = final h (f32 row-major); hidden aliases the bf16 buffers.
    mlp_kernel<<<(N + 63) / 64, 256, 0, stream>>>(hfin, W1, b1, hidden, N, 1);
    mlp_kernel<<<(N + 63) / 64, 256, 0, stream>>>(hidden, W2, b2, out, N, 0);
}